// Round 17
// baseline (720.127 us; speedup 1.0000x reference)
//
#include <hip/hip_runtime.h>
#include <hip/hip_bf16.h>

constexpr int B_ = 8;
constexpr int N_ = 1024;      // nodes
constexpr int C_ = 128;       // channels
constexpr int EL_ = 196;      // local edges
constexpr int ET_ = N_ + EL_; // 1220 total edges
constexpr int RT_ = N_ + ET_; // 2244 rows (node+edge) per batch
constexpr int KNN_ = 11;      // k+1
constexpr int CAP_ = 512;     // per-node edge-list capacity (u16 entries)
constexpr int CAP2_ = 512;    // per-edge member capacity
constexpr int HT_ = 64;       // heavy-row threshold
constexpr int MAXH_ = 512;    // heavy rows/batch bound
constexpr int XMS_ = N_ + 1;  // X mirror rows/batch (last = zero pad row)
constexpr int EMS_ = ET_ + 1; // E mirror rows/batch (last = zero pad row)
constexpr int PADN_ = N_;     // pad index into X mirror
constexpr int PADE_ = ET_;    // pad index into E mirror

// ---------------- x2 = sum(x*x) per row ----------------
__global__ void k_x2(const float* __restrict__ X, float* __restrict__ x2) {
    int row = blockIdx.x * 4 + (threadIdx.x >> 6);
    int lane = threadIdx.x & 63;
    const float* xr = X + (size_t)row * C_;
    float a = xr[lane], b = xr[lane + 64];
    float s = a * a + b * b;
    #pragma unroll
    for (int off = 32; off > 0; off >>= 1) s += __shfl_down(s, off, 64);
    if (lane == 0) x2[row] = s;
}

// ---------------- distance matrix: tiled 128x128 GEMM, batch-per-XCD ----------
__global__ __launch_bounds__(256) void k_dist(const float* __restrict__ X,
                                              const float* __restrict__ x2,
                                              float* __restrict__ D) {
    __shared__ float As[32][132];
    __shared__ float Bs[32][132];
    int b = blockIdx.x & 7;
    int t = blockIdx.x >> 3;
    int ti = t >> 3, tj = t & 7;
    const float* Xb = X + (size_t)b * N_ * C_;
    int tid = threadIdx.x;
    int tx = tid & 15, ty = tid >> 4;
    float acc[8][8];
    #pragma unroll
    for (int i = 0; i < 8; ++i)
        #pragma unroll
        for (int j = 0; j < 8; ++j) acc[i][j] = 0.f;
    for (int kc = 0; kc < 4; ++kc) {
        __syncthreads();
        #pragma unroll
        for (int q = 0; q < 4; ++q) {
            int id = tid + q * 256;
            int r = id >> 3, kk = (id & 7) * 4;
            float4 av = *(const float4*)(Xb + (size_t)(ti * 128 + r) * C_ + kc * 32 + kk);
            As[kk + 0][r] = av.x; As[kk + 1][r] = av.y;
            As[kk + 2][r] = av.z; As[kk + 3][r] = av.w;
            float4 bv = *(const float4*)(Xb + (size_t)(tj * 128 + r) * C_ + kc * 32 + kk);
            Bs[kk + 0][r] = bv.x; Bs[kk + 1][r] = bv.y;
            Bs[kk + 2][r] = bv.z; Bs[kk + 3][r] = bv.w;
        }
        __syncthreads();
        #pragma unroll 8
        for (int k = 0; k < 32; ++k) {
            float a[8], bb[8];
            *(float4*)(a + 0) = *(const float4*)&As[k][ty * 8];
            *(float4*)(a + 4) = *(const float4*)&As[k][ty * 8 + 4];
            *(float4*)(bb + 0) = *(const float4*)&Bs[k][tx * 8];
            *(float4*)(bb + 4) = *(const float4*)&Bs[k][tx * 8 + 4];
            #pragma unroll
            for (int i = 0; i < 8; ++i)
                #pragma unroll
                for (int j = 0; j < 8; ++j) acc[i][j] += a[i] * bb[j];
        }
    }
    float x2r[8], x2c[8];
    #pragma unroll
    for (int i = 0; i < 8; ++i) x2r[i] = x2[b * N_ + ti * 128 + ty * 8 + i];
    #pragma unroll
    for (int j = 0; j < 8; ++j) x2c[j] = x2[b * N_ + tj * 128 + tx * 8 + j];
    #pragma unroll
    for (int i = 0; i < 8; ++i) {
        int m = ti * 128 + ty * 8 + i;
        float* drow = D + ((size_t)(b * N_ + m)) * N_ + tj * 128 + tx * 8;
        float4 o0, o1;
        o0.x = x2r[i] - 2.f * acc[i][0] + x2c[0];
        o0.y = x2r[i] - 2.f * acc[i][1] + x2c[1];
        o0.z = x2r[i] - 2.f * acc[i][2] + x2c[2];
        o0.w = x2r[i] - 2.f * acc[i][3] + x2c[3];
        o1.x = x2r[i] - 2.f * acc[i][4] + x2c[4];
        o1.y = x2r[i] - 2.f * acc[i][5] + x2c[5];
        o1.z = x2r[i] - 2.f * acc[i][6] + x2c[6];
        o1.w = x2r[i] - 2.f * acc[i][7] + x2c[7];
        *(float4*)drow = o0;
        *(float4*)(drow + 4) = o1;
    }
}

// monotone map: float total order -> u32 unsigned order
__device__ __forceinline__ unsigned mapdist(float d) {
    unsigned u = __float_as_uint(d);
    return u ^ (unsigned)(((int)u >> 31) | 0x80000000);
}

// wave-parallel top-m selection thresholds; replicates stable argsort exactly
struct SelThresh { unsigned theta; unsigned psi; };

__device__ __forceinline__ SelThresh wave_topm(const unsigned (&md)[16],
                                               const int (&col)[16], int m) {
    unsigned pfx = 0;
    for (int b = 31; b >= 0; --b) {
        unsigned cand = pfx | (1u << b);
        int c = 0;
        #pragma unroll
        for (int i = 0; i < 16; ++i)
            c += __popcll(__ballot(md[i] < cand));
        if (c < m) pfx = cand;
    }
    unsigned theta = pfx;
    int cLt = 0;
    #pragma unroll
    for (int i = 0; i < 16; ++i)
        cLt += __popcll(__ballot(md[i] < theta));
    int t = m - cLt;  // >= 1
    unsigned ppfx = 0;
    for (int b = 9; b >= 0; --b) {
        unsigned cand = ppfx | (1u << b);
        int c = 0;
        #pragma unroll
        for (int i = 0; i < 16; ++i)
            c += __popcll(__ballot(md[i] == theta && (unsigned)col[i] < cand));
        if (c < t) ppfx = cand;
    }
    return {theta, ppfx};
}

__device__ __forceinline__ void load_row16(const float* __restrict__ Drow, int lane,
                                           unsigned (&md)[16], int (&col)[16]) {
    const float4* row4 = (const float4*)Drow;
    #pragma unroll
    for (int j = 0; j < 4; ++j) {
        float4 v = row4[j * 64 + lane];
        int c0 = (j * 64 + lane) * 4;
        md[j * 4 + 0] = mapdist(v.x); col[j * 4 + 0] = c0 + 0;
        md[j * 4 + 1] = mapdist(v.y); col[j * 4 + 1] = c0 + 1;
        md[j * 4 + 2] = mapdist(v.z); col[j * 4 + 2] = c0 + 2;
        md[j * 4 + 3] = mapdist(v.w); col[j * 4 + 3] = c0 + 3;
    }
}

// ------ top-11 per row -> Dv atomics (wave/row, radix select, batch-XCD) -------
__global__ __launch_bounds__(256) void k_top11dv(const float* __restrict__ D,
                                                 int* __restrict__ Dv) {
    int b = blockIdx.x & 7;
    int n = ((blockIdx.x >> 3) << 2) + (threadIdx.x >> 6);
    int lane = threadIdx.x & 63;
    int w = b * N_ + n;
    unsigned md[16]; int col[16];
    load_row16(D + (size_t)w * N_, lane, md, col);
    SelThresh st = wave_topm(md, col, KNN_);
    #pragma unroll
    for (int i = 0; i < 16; ++i) {
        bool in = (md[i] < st.theta) || (md[i] == st.theta && (unsigned)col[i] <= st.psi);
        if (in) atomicAdd(&Dv[b * N_ + col[i]], 1);
    }
}

// ------- local edge member lists: wave per edge, ordered compaction + pad16 ----
__global__ void k_locbuild(const float* __restrict__ localH, int* __restrict__ locCnt,
                           unsigned short* __restrict__ locList) {
    int w = (blockIdx.x * blockDim.x + threadIdx.x) >> 6;
    int lane = threadIdx.x & 63;
    if (w >= EL_) return;
    int le = w;
    int base = 0;
    for (int chunk = 0; chunk < N_ / 64; ++chunk) {
        int n = chunk * 64 + lane;
        bool m = localH[(size_t)n * EL_ + le] != 0.0f;
        unsigned long long mask = __ballot(m);
        if (m) {
            int pos = base + __popcll(mask & ((1ull << lane) - 1ull));
            locList[le * 32 + pos] = (unsigned short)n;
        }
        base += __popcll(mask);
    }
    int cp = (base + 15) & ~15;   // 16-pad (max cnt 25 -> cp 32 == stride)
    for (int t = base + lane; t < cp; t += 64)
        locList[le * 32 + t] = (unsigned short)PADN_;
    if (lane == 0) locCnt[le] = base;
}

// - edge member selection (radix) + ballot-compact + pad16 + scatter (batch-XCD)
__global__ __launch_bounds__(256) void k_edgebuild(const float* __restrict__ D,
                                                   const int* __restrict__ Dv,
                                                   const int* __restrict__ locCnt,
                                                   const unsigned short* __restrict__ locList,
                                                   unsigned short* __restrict__ edgeMem,
                                                   int* __restrict__ nodeCnt,
                                                   unsigned short* __restrict__ nodeList,
                                                   float* __restrict__ recipDE) {
    int b = blockIdx.x & 7;
    int e = ((blockIdx.x >> 3) << 2) + (threadIdx.x >> 6);
    int lane = threadIdx.x & 63;
    if (e >= ET_) return;
    int w = b * ET_ + e;
    if (e < N_) {
        int rn = b * N_ + e;
        int full = Dv[rn];
        int m = full < CAP2_ ? full : CAP2_;
        unsigned md[16]; int col[16];
        load_row16(D + (size_t)rn * N_, lane, md, col);
        SelThresh st = wave_topm(md, col, m);
        int base = 0;
        #pragma unroll
        for (int i = 0; i < 16; ++i) {
            bool in = (md[i] < st.theta) || (md[i] == st.theta && (unsigned)col[i] <= st.psi);
            unsigned long long bal = __ballot(in);
            if (in) {
                int pos = base + __popcll(bal & ((1ull << lane) - 1ull));
                edgeMem[(size_t)rn * CAP2_ + pos] = (unsigned short)col[i];
                int p2 = atomicAdd(&nodeCnt[b * N_ + col[i]], 1);
                if (p2 < CAP_) nodeList[((size_t)(b * N_ + col[i])) * CAP_ + p2] = (unsigned short)e;
            }
            base += __popcll(bal);
        }
        int cp = (m + 15) & ~15;
        for (int t = m + lane; t < cp; t += 64)
            edgeMem[(size_t)rn * CAP2_ + t] = (unsigned short)PADN_;
        if (lane == 0) recipDE[w] = 1.0f / (float)full;
    } else {
        int le = e - N_;
        int cnt = locCnt[le];
        for (int t = lane; t < cnt; t += 64) {
            int j = locList[le * 32 + t];
            int pos = atomicAdd(&nodeCnt[b * N_ + j], 1);
            if (pos < CAP_) nodeList[((size_t)(b * N_ + j)) * CAP_ + pos] = (unsigned short)e;
        }
        if (lane == 0) recipDE[w] = 1.0f / (float)cnt;
    }
}

// --- wave-per-node rank sort + pad16 + recipDV + heavy-row registration --------
__global__ __launch_bounds__(256) void k_sortlists(int* __restrict__ nodeCnt,
                                                   unsigned short* __restrict__ nodeList,
                                                   float* __restrict__ recipDV,
                                                   const int* __restrict__ Dv,
                                                   int* __restrict__ heavyCnt,
                                                   unsigned* __restrict__ heavyList) {
    __shared__ int sl[4][CAP_];
    int w = threadIdx.x >> 6;
    int lane = threadIdx.x & 63;
    int rn = blockIdx.x * 4 + w;
    int cnt = nodeCnt[rn];
    if (cnt > CAP_) cnt = CAP_;
    unsigned short* g = nodeList + (size_t)rn * CAP_;
    for (int t = lane; t < cnt; t += 64) sl[w][t] = g[t];
    __syncthreads();
    for (int t = lane; t < cnt; t += 64) {
        int v = sl[w][t];
        int rank = 0;
        for (int j = 0; j < cnt; ++j) rank += (sl[w][j] < v) ? 1 : 0;
        g[rank] = (unsigned short)v;
    }
    int cp = (cnt + 15) & ~15;
    if (cp > CAP_) cp = CAP_;
    for (int t = cnt + lane; t < cp; t += 64)
        g[t] = (unsigned short)PADE_;
    if (lane == 0) {
        recipDV[rn] = 1.0f / (float)cnt;
        nodeCnt[rn] = cnt;
        int b = rn >> 10, n = rn & 1023;
        if (cnt > HT_) {
            int p = atomicAdd(&heavyCnt[b], 1);
            if (p < MAXH_) heavyList[b * MAXH_ + p] = (unsigned)n;           // side 0: node
        }
        int ec = Dv[rn];
        if (ec > CAP2_) ec = CAP2_;
        if (ec > HT_) {
            int p = atomicAdd(&heavyCnt[b], 1);
            if (p < MAXH_) heavyList[b * MAXH_ + p] = 0x10000u | (unsigned)n; // side 1: edge
        }
    }
}

// ---------------- fp32 16-way ILP gather (used by k_einit only; exact cnt) -----
__device__ __forceinline__ float2 gather16(const float* __restrict__ base,
                                           const unsigned short* __restrict__ src,
                                           int cnt, int lane) {
    float2 a0 = {0.f, 0.f}, a1 = {0.f, 0.f}, a2 = {0.f, 0.f}, a3 = {0.f, 0.f};
    const float* bl = base + 2 * lane;
    int t = 0;
    for (; t + 8 <= cnt; t += 8) {
        uint4 u = *(const uint4*)(src + t);
        float2 v0 = *(const float2*)(bl + (size_t)(u.x & 0xFFFFu) * C_);
        float2 v1 = *(const float2*)(bl + (size_t)(u.x >> 16) * C_);
        float2 v2 = *(const float2*)(bl + (size_t)(u.y & 0xFFFFu) * C_);
        float2 v3 = *(const float2*)(bl + (size_t)(u.y >> 16) * C_);
        float2 v4 = *(const float2*)(bl + (size_t)(u.z & 0xFFFFu) * C_);
        float2 v5 = *(const float2*)(bl + (size_t)(u.z >> 16) * C_);
        float2 v6 = *(const float2*)(bl + (size_t)(u.w & 0xFFFFu) * C_);
        float2 v7 = *(const float2*)(bl + (size_t)(u.w >> 16) * C_);
        a0.x += v0.x + v4.x; a0.y += v0.y + v4.y;
        a1.x += v1.x + v5.x; a1.y += v1.y + v5.y;
        a2.x += v2.x + v6.x; a2.y += v2.y + v6.y;
        a3.x += v3.x + v7.x; a3.y += v3.y + v7.y;
    }
    for (; t < cnt; ++t) {
        float2 v = *(const float2*)(bl + (size_t)src[t] * C_);
        a0.x += v.x; a0.y += v.y;
    }
    a0.x += a1.x + a2.x + a3.x;
    a0.y += a1.y + a2.y + a3.y;
    return a0;
}

// ---------------- bf16 mirror helpers ----------------
__device__ __forceinline__ float2 bf2f(unsigned q) {
    return make_float2(__uint_as_float(q << 16), __uint_as_float(q & 0xffff0000u));
}
__device__ __forceinline__ unsigned pack_bf(float x, float y) {
    unsigned ux = __float_as_uint(x), uy = __float_as_uint(y);
    ux += 0x7fffu + ((ux >> 16) & 1u);
    uy += 0x7fffu + ((uy >> 16) & 1u);
    return (ux >> 16) | (uy & 0xffff0000u);
}

// bf16 gather over 16-PADDED list: cntP multiple of 16 (pads hit zero row).
// 16 outstanding row loads per iteration -> typical row = ONE dependent batch.
__device__ __forceinline__ float2 gather16h(const unsigned* __restrict__ base,
                                            const unsigned short* __restrict__ src,
                                            int cntP, int lane) {
    float2 a0 = {0.f, 0.f}, a1 = {0.f, 0.f}, a2 = {0.f, 0.f}, a3 = {0.f, 0.f};
    const unsigned* bl = base + lane;
    for (int t = 0; t < cntP; t += 16) {
        uint4 u0 = *(const uint4*)(src + t);
        uint4 u1 = *(const uint4*)(src + t + 8);
        unsigned q0 = bl[(size_t)(u0.x & 0xFFFFu) * 64];
        unsigned q1 = bl[(size_t)(u0.x >> 16) * 64];
        unsigned q2 = bl[(size_t)(u0.y & 0xFFFFu) * 64];
        unsigned q3 = bl[(size_t)(u0.y >> 16) * 64];
        unsigned q4 = bl[(size_t)(u0.z & 0xFFFFu) * 64];
        unsigned q5 = bl[(size_t)(u0.z >> 16) * 64];
        unsigned q6 = bl[(size_t)(u0.w & 0xFFFFu) * 64];
        unsigned q7 = bl[(size_t)(u0.w >> 16) * 64];
        unsigned q8 = bl[(size_t)(u1.x & 0xFFFFu) * 64];
        unsigned q9 = bl[(size_t)(u1.x >> 16) * 64];
        unsigned qa = bl[(size_t)(u1.y & 0xFFFFu) * 64];
        unsigned qb = bl[(size_t)(u1.y >> 16) * 64];
        unsigned qc = bl[(size_t)(u1.z & 0xFFFFu) * 64];
        unsigned qd = bl[(size_t)(u1.z >> 16) * 64];
        unsigned qe = bl[(size_t)(u1.w & 0xFFFFu) * 64];
        unsigned qf = bl[(size_t)(u1.w >> 16) * 64];
        float2 v0 = bf2f(q0), v1 = bf2f(q1), v2 = bf2f(q2), v3 = bf2f(q3);
        float2 v4 = bf2f(q4), v5 = bf2f(q5), v6 = bf2f(q6), v7 = bf2f(q7);
        float2 v8 = bf2f(q8), v9 = bf2f(q9), va = bf2f(qa), vb = bf2f(qb);
        float2 vc = bf2f(qc), vd = bf2f(qd), ve = bf2f(qe), vf = bf2f(qf);
        a0.x += v0.x + v4.x + v8.x + vc.x; a0.y += v0.y + v4.y + v8.y + vc.y;
        a1.x += v1.x + v5.x + v9.x + vd.x; a1.y += v1.y + v5.y + v9.y + vd.y;
        a2.x += v2.x + v6.x + va.x + ve.x; a2.y += v2.y + v6.y + va.y + ve.y;
        a3.x += v3.x + v7.x + vb.x + vf.x; a3.y += v3.y + v7.y + vb.y + vf.y;
    }
    a0.x += a1.x + a2.x + a3.x;
    a0.y += a1.y + a2.y + a3.y;
    return a0;
}

__device__ __forceinline__ void edge_src(const unsigned short* __restrict__ edgeMem,
                                         const int* __restrict__ Dv,
                                         const int* __restrict__ locCnt,
                                         const unsigned short* __restrict__ locList,
                                         int b, int e,
                                         const unsigned short*& src, int& cnt) {
    if (e < N_) {
        int rn = b * N_ + e;
        cnt = Dv[rn];
        if (cnt > CAP2_) cnt = CAP2_;
        src = edgeMem + (size_t)rn * CAP2_;
    } else {
        cnt = locCnt[e - N_];
        src = locList + (e - N_) * 32;
    }
}

// ---------------- E init: E0 = W_ev @ X (fp32 gather; one-shot) ----------------
__global__ void k_einit(const float* __restrict__ Xsrc, float* __restrict__ Edst,
                        const unsigned short* __restrict__ edgeMem, const int* __restrict__ Dv,
                        const int* __restrict__ locCnt, const unsigned short* __restrict__ locList,
                        const float* __restrict__ recipDE) {
    int b = blockIdx.x & 7;
    int e = (blockIdx.x >> 3) * 2 + (threadIdx.x >> 6);
    int lane = threadIdx.x & 63;
    if (e >= ET_) return;
    int w = b * ET_ + e;
    const unsigned short* src; int cnt;
    edge_src(edgeMem, Dv, locCnt, locList, b, e, src, cnt);
    float2 acc = gather16(Xsrc + (size_t)b * N_ * C_, src, cnt, lane);
    float r = recipDE[w];
    *(float2*)(Edst + (size_t)w * C_ + 2 * lane) = make_float2(r * acc.x, r * acc.y);
}

// -- fused diffusion step: heavy blocks FIRST (longest-running start earliest) --
constexpr int HEAVYB_ = 8 * MAXH_;             // 4096
constexpr int LIGHTB_ = B_ * ((RT_ + 7) / 8);  // 2248
__global__ __launch_bounds__(512) void k_step(float* __restrict__ X,
                                              float* __restrict__ E,
                                              const unsigned* __restrict__ XhSrc,
                                              const unsigned* __restrict__ EhSrc,
                                              unsigned* __restrict__ XhDst,
                                              unsigned* __restrict__ EhDst,
                                              const unsigned short* __restrict__ edgeMem,
                                              const int* __restrict__ Dv,
                                              const int* __restrict__ locCnt,
                                              const unsigned short* __restrict__ locList,
                                              const int* __restrict__ nodeCnt,
                                              const unsigned short* __restrict__ nodeList,
                                              const float* __restrict__ recipDV,
                                              const float* __restrict__ recipDE,
                                              const int* __restrict__ heavyCnt,
                                              const unsigned* __restrict__ heavyList) {
    __shared__ float2 ps[8][64];
    int lane = threadIdx.x & 63;
    int wid = threadIdx.x >> 6;
    if (blockIdx.x >= (unsigned)HEAVYB_) {
        unsigned u = blockIdx.x - HEAVYB_;
        int b = u & 7;
        int local = (int)((u >> 3) << 3) + wid;  // 0..RT_-1 (+pad)
        if (local >= RT_) return;
        if (local < N_) {
            int rn = b * N_ + local;
            int cnt = nodeCnt[rn];
            if (cnt > HT_) return;  // heavy block handles
            float2 acc = gather16h(EhSrc + (size_t)b * EMS_ * 64, nodeList + (size_t)rn * CAP_,
                                   (cnt + 15) & ~15, lane);
            size_t o = (size_t)rn * C_ + 2 * lane;
            float2 xv = *(const float2*)(X + o);
            float s = 0.05f * recipDV[rn];
            float rx = 0.95f * xv.x + s * acc.x, ry = 0.95f * xv.y + s * acc.y;
            *(float2*)(X + o) = make_float2(rx, ry);
            XhDst[((size_t)b * XMS_ + local) * 64 + lane] = pack_bf(rx, ry);
        } else {
            int e = local - N_;
            int be = b * ET_ + e;
            const unsigned short* src; int cnt;
            edge_src(edgeMem, Dv, locCnt, locList, b, e, src, cnt);
            if (cnt > HT_) return;  // heavy block handles
            float2 acc = gather16h(XhSrc + (size_t)b * XMS_ * 64, src, (cnt + 15) & ~15, lane);
            size_t o = (size_t)be * C_ + 2 * lane;
            float2 ev = *(const float2*)(E + o);
            float s = 0.9f * recipDE[be];
            float rx = 0.1f * ev.x + s * acc.x, ry = 0.1f * ev.y + s * acc.y;
            *(float2*)(E + o) = make_float2(rx, ry);
            EhDst[((size_t)b * EMS_ + e) * 64 + lane] = pack_bf(rx, ry);
        }
    } else {
        int hb = blockIdx.x;
        int b = hb & 7;
        int idx = hb >> 3;
        if (idx >= heavyCnt[b]) return;        // whole-block uniform return
        unsigned enc = heavyList[b * MAXH_ + idx];
        int side = (int)(enc >> 16), n = (int)(enc & 0xFFFFu);
        const unsigned short* src;
        const unsigned* gbase;
        const float* fsrc;
        float scale, selfw;
        size_t orow, mrow;
        int cnt;
        if (side == 0) {  // node n
            int rn = b * N_ + n;
            cnt = nodeCnt[rn];
            src = nodeList + (size_t)rn * CAP_;
            gbase = EhSrc + (size_t)b * EMS_ * 64;
            scale = 0.05f * recipDV[rn]; selfw = 0.95f;
            orow = (size_t)rn * C_; fsrc = X;
            mrow = ((size_t)b * XMS_ + n) * 64;
        } else {          // kNN edge e = n
            int rn = b * N_ + n;
            int be = b * ET_ + n;
            cnt = Dv[rn]; if (cnt > CAP2_) cnt = CAP2_;
            src = edgeMem + (size_t)rn * CAP2_;
            gbase = XhSrc + (size_t)b * XMS_ * 64;
            scale = 0.9f * recipDE[be]; selfw = 0.1f;
            orow = (size_t)be * C_; fsrc = E;
            mrow = ((size_t)b * EMS_ + n) * 64;
        }
        int cntP = (cnt + 15) & ~15;
        if (cntP > CAP_) cntP = CAP_;
        int nb16 = cntP >> 4;
        int per = (((nb16 + 7) >> 3)) << 4;  // 16-aligned per-wave slice
        int st = wid * per;
        int ln = cntP - st;
        if (ln < 0) ln = 0;
        if (ln > per) ln = per;
        ps[wid][lane] = gather16h(gbase, src + st, ln, lane);
        __syncthreads();
        if (wid == 0) {
            float ax = 0.f, ay = 0.f;
            #pragma unroll
            for (int q = 0; q < 8; ++q) { ax += ps[q][lane].x; ay += ps[q][lane].y; }
            float2 sv = *(const float2*)(fsrc + orow + 2 * lane);
            float rx = selfw * sv.x + scale * ax, ry = selfw * sv.y + scale * ay;
            float* fdst = (side == 0) ? (float*)X : (float*)E;
            unsigned* hdst = (side == 0) ? XhDst : EhDst;
            *(float2*)(fdst + orow + 2 * lane) = make_float2(rx, ry);
            hdst[mrow + lane] = pack_bf(rx, ry);
        }
    }
}

// ------- Z = Z + relu(Z @ W^T + bias): 16 rows/block, W amortized 16x ---------
constexpr int XB_ = B_ * N_ / 16;   // 512
constexpr int EB_ = B_ * ET_ / 16;  // 610
__global__ __launch_bounds__(128) void k_transform(float* __restrict__ Xz,
                                                   float* __restrict__ Ez,
                                                   const float* __restrict__ tvw,
                                                   const float* __restrict__ tvb,
                                                   const float* __restrict__ tew,
                                                   const float* __restrict__ teb) {
    __shared__ __align__(16) float zs[16][C_];
    int blk = blockIdx.x;
    float* Z;
    const float *W, *bias;
    if (blk < XB_) { Z = Xz + (size_t)blk * 16 * C_; W = tvw; bias = tvb; }
    else { Z = Ez + (size_t)(blk - XB_) * 16 * C_; W = tew; bias = teb; }
    int c = threadIdx.x;
    const float4* Zg4 = (const float4*)Z;
    float4* zs4 = (float4*)zs;
    #pragma unroll
    for (int q = 0; q < 4; ++q) zs4[c + q * 128] = Zg4[c + q * 128];
    __syncthreads();
    float acc[16];
    float bc = bias[c];
    #pragma unroll
    for (int r = 0; r < 16; ++r) acc[r] = bc;
    const float4* w4 = (const float4*)(W + (size_t)c * C_);
    #pragma unroll 4
    for (int k = 0; k < 32; ++k) {
        float4 w = w4[k];
        #pragma unroll
        for (int r = 0; r < 16; ++r) {
            float4 z = ((const float4*)zs[r])[k];
            acc[r] += w.x * z.x + w.y * z.y + w.z * z.z + w.w * z.w;
        }
    }
    #pragma unroll
    for (int r = 0; r < 16; ++r)
        Z[(size_t)r * C_ + c] = zs[r][c] + fmaxf(acc[r], 0.f);
}

// ---- bn_nodes: per-position norm over (B, C); also refreshes bf16 mirrors -----
__global__ void k_bn(float* __restrict__ Xz, float* __restrict__ Ez,
                     unsigned* __restrict__ Xh, unsigned* __restrict__ Eh) {
    int pos = blockIdx.x;
    float* Z;
    unsigned* Zh;
    int P, MS;
    if (pos < N_) { Z = Xz; Zh = Xh; P = N_; MS = XMS_; }
    else { Z = Ez; Zh = Eh; P = ET_; MS = EMS_; pos -= N_; }
    int t = threadIdx.x;
    __shared__ float red[256];
    float2 v[2];
    #pragma unroll
    for (int q = 0; q < 2; ++q) {
        int f = t + q * 256;
        int b = f >> 6, cp = f & 63;
        v[q] = *(const float2*)(Z + ((size_t)(b * P + pos)) * C_ + 2 * cp);
    }
    red[t] = v[0].x + v[0].y + v[1].x + v[1].y;
    __syncthreads();
    for (int off = 128; off > 0; off >>= 1) {
        if (t < off) red[t] += red[t + off];
        __syncthreads();
    }
    float m = red[0] * (1.0f / 1024.0f);
    __syncthreads();
    float s2 = 0.f;
    #pragma unroll
    for (int q = 0; q < 2; ++q) {
        float dx = v[q].x - m, dy = v[q].y - m;
        s2 += dx * dx + dy * dy;
    }
    red[t] = s2;
    __syncthreads();
    for (int off = 128; off > 0; off >>= 1) {
        if (t < off) red[t] += red[t + off];
        __syncthreads();
    }
    float rstd = rsqrtf(red[0] * (1.0f / 1024.0f) + 1e-5f);
    #pragma unroll
    for (int q = 0; q < 2; ++q) {
        int f = t + q * 256;
        int b = f >> 6, cp = f & 63;
        float rx = (v[q].x - m) * rstd, ry = (v[q].y - m) * rstd;
        *(float2*)(Z + ((size_t)(b * P + pos)) * C_ + 2 * cp) = make_float2(rx, ry);
        Zh[((size_t)b * MS + pos) * 64 + cp] = pack_bf(rx, ry);
    }
}

// ---------------- final per-channel stats over (B,N) ----------------
__global__ void k_finstats(const float* __restrict__ Xf, float* __restrict__ stats) {
    int c = blockIdx.x;
    int t = threadIdx.x;
    __shared__ float rs[256], rs2[256];
    float s = 0.f, s2 = 0.f;
    for (int r = t; r < B_ * N_; r += 256) {
        float x = Xf[(size_t)r * C_ + c];
        s += x;
        s2 += x * x;
    }
    rs[t] = s; rs2[t] = s2;
    __syncthreads();
    for (int off = 128; off > 0; off >>= 1) {
        if (t < off) { rs[t] += rs[t + off]; rs2[t] += rs2[t + off]; }
        __syncthreads();
    }
    if (t == 0) {
        float m = rs[0] / (float)(B_ * N_);
        float var = rs2[0] / (float)(B_ * N_) - m * m;
        stats[c] = m;
        stats[C_ + c] = rsqrtf(var + 1e-5f);
    }
}

__global__ void k_finapply(const float* __restrict__ Xf, const float* __restrict__ Xin,
                           const float* __restrict__ stats, const float* __restrict__ bnw,
                           const float* __restrict__ bnb, float* __restrict__ out) {
    size_t i = (size_t)blockIdx.x * blockDim.x + threadIdx.x;
    if (i >= (size_t)B_ * N_ * C_) return;
    int c = (int)(i & (C_ - 1));
    float x = Xf[i];
    float xn = (x - stats[c]) * stats[C_ + c] * bnw[c] + bnb[c];
    out[i] = fmaxf(xn, 0.f) + Xin[i];
}

extern "C" void kernel_launch(void* const* d_in, const int* in_sizes, int n_in,
                              void* d_out, int out_size, void* d_ws, size_t ws_size,
                              hipStream_t stream) {
    const float* Xin = (const float*)d_in[0];
    const float* localH = (const float*)d_in[1];
    const float* tv_w = (const float*)d_in[2];
    const float* tv_b = (const float*)d_in[3];
    const float* te_w = (const float*)d_in[4];
    const float* te_b = (const float*)d_in[5];
    const float* bn_w = (const float*)d_in[6];
    const float* bn_b = (const float*)d_in[7];
    float* out = (float*)d_out;

    char* base = (char*)d_ws;
    size_t off = 0;
    auto alloc = [&](size_t bytes) -> void* {
        void* p = base + off;
        off = (off + bytes + 255) & ~(size_t)255;
        return p;
    };
    float* D = (float*)alloc((size_t)B_ * N_ * N_ * 4);
    float* x2 = (float*)alloc((size_t)B_ * N_ * 4);
    int* Dv = (int*)alloc((size_t)B_ * N_ * 4);
    int* nodeCnt = (int*)alloc((size_t)B_ * N_ * 4);
    unsigned short* nodeList = (unsigned short*)alloc((size_t)B_ * N_ * CAP_ * 2);
    float* recipDV = (float*)alloc((size_t)B_ * N_ * 4);
    float* recipDE = (float*)alloc((size_t)B_ * ET_ * 4);
    int* locCnt = (int*)alloc(256 * 4);
    unsigned short* locList = (unsigned short*)alloc((size_t)EL_ * 32 * 2);
    unsigned short* edgeMem = (unsigned short*)alloc((size_t)B_ * N_ * CAP2_ * 2);
    int* heavyCnt = (int*)alloc(B_ * 4);
    unsigned* heavyList = (unsigned*)alloc((size_t)B_ * MAXH_ * 4);
    float* X0 = (float*)alloc((size_t)B_ * N_ * C_ * 4);
    float* E0 = (float*)alloc((size_t)B_ * ET_ * C_ * 4);
    unsigned* Xh0 = (unsigned*)alloc((size_t)B_ * XMS_ * 64 * 4);
    unsigned* Xh1 = (unsigned*)alloc((size_t)B_ * XMS_ * 64 * 4);
    unsigned* Eh0 = (unsigned*)alloc((size_t)B_ * EMS_ * 64 * 4);
    unsigned* Eh1 = (unsigned*)alloc((size_t)B_ * EMS_ * 64 * 4);
    float* stats = (float*)alloc(2 * C_ * 4);
    if (off > ws_size) return;

    hipMemsetAsync(Dv, 0, (size_t)B_ * N_ * 4, stream);
    hipMemsetAsync(nodeCnt, 0, (size_t)B_ * N_ * 4, stream);
    hipMemsetAsync(heavyCnt, 0, B_ * 4, stream);
    // zero mirror buffers once: pad rows must stay zero across all steps
    hipMemsetAsync(Xh0, 0, (size_t)B_ * XMS_ * 64 * 4, stream);
    hipMemsetAsync(Xh1, 0, (size_t)B_ * XMS_ * 64 * 4, stream);
    hipMemsetAsync(Eh0, 0, (size_t)B_ * EMS_ * 64 * 4, stream);
    hipMemsetAsync(Eh1, 0, (size_t)B_ * EMS_ * 64 * 4, stream);
    hipMemcpyAsync(X0, Xin, (size_t)B_ * N_ * C_ * 4, hipMemcpyDeviceToDevice, stream);

    k_x2<<<B_ * N_ / 4, 256, 0, stream>>>(Xin, x2);
    k_dist<<<B_ * 64, 256, 0, stream>>>(Xin, x2, D);
    k_top11dv<<<B_ * (N_ / 4), 256, 0, stream>>>(D, Dv);
    k_locbuild<<<(EL_ * 64 + 255) / 256, 256, 0, stream>>>(localH, locCnt, locList);
    k_edgebuild<<<B_ * ((ET_ + 3) / 4), 256, 0, stream>>>(D, Dv, locCnt, locList, edgeMem,
                                                          nodeCnt, nodeList, recipDE);
    k_sortlists<<<B_ * N_ / 4, 256, 0, stream>>>(nodeCnt, nodeList, recipDV, Dv,
                                                 heavyCnt, heavyList);
    k_einit<<<B_ * (ET_ / 2 + 1), 128, 0, stream>>>(X0, E0, edgeMem, Dv, locCnt, locList,
                                                    recipDE);

    unsigned* Xhc = Xh0; unsigned* Xhn = Xh1; unsigned* Ehc = Eh0; unsigned* Ehn = Eh1;
    const int STEPG = HEAVYB_ + LIGHTB_;
    for (int i = 0; i < 40; ++i) {
        if (i % 20 == 0) {
            k_transform<<<XB_ + EB_, 128, 0, stream>>>(X0, E0, tv_w, tv_b, te_w, te_b);
            k_bn<<<N_ + ET_, 256, 0, stream>>>(X0, E0, Xhc, Ehc);
        }
        k_step<<<STEPG, 512, 0, stream>>>(X0, E0, Xhc, Ehc, Xhn, Ehn,
                                          edgeMem, Dv, locCnt, locList, nodeCnt,
                                          nodeList, recipDV, recipDE, heavyCnt, heavyList);
        unsigned* th;
        th = Xhc; Xhc = Xhn; Xhn = th;
        th = Ehc; Ehc = Ehn; Ehn = th;
    }

    k_finstats<<<C_, 256, 0, stream>>>(X0, stats);
    k_finapply<<<(B_ * N_ * C_ + 255) / 256, 256, 0, stream>>>(X0, Xin, stats, bn_w, bn_b, out);
}

// Round 18
// 655.124 us; speedup vs baseline: 1.0992x; 1.0992x over previous
//
#include <hip/hip_runtime.h>
#include <hip/hip_bf16.h>

constexpr int B_ = 8;
constexpr int N_ = 1024;      // nodes
constexpr int C_ = 128;       // channels
constexpr int EL_ = 196;      // local edges
constexpr int ET_ = N_ + EL_; // 1220 total edges
constexpr int RT_ = N_ + ET_; // 2244 rows (node+edge) per batch
constexpr int KNN_ = 11;      // k+1
constexpr int CAP_ = 512;     // per-node edge-list capacity (u16 entries)
constexpr int CAP2_ = 512;    // per-edge member capacity
constexpr int HT_ = 64;       // heavy-row threshold
constexpr int MAXH_ = 512;    // heavy rows/batch bound
constexpr int XMS_ = N_ + 1;  // X mirror rows/batch (last = zero pad row)
constexpr int EMS_ = ET_ + 1; // E mirror rows/batch (last = zero pad row)
constexpr int PADN_ = N_;     // pad index into X mirror
constexpr int PADE_ = ET_;    // pad index into E mirror

// ---------------- x2 = sum(x*x) per row ----------------
__global__ void k_x2(const float* __restrict__ X, float* __restrict__ x2) {
    int row = blockIdx.x * 4 + (threadIdx.x >> 6);
    int lane = threadIdx.x & 63;
    const float* xr = X + (size_t)row * C_;
    float a = xr[lane], b = xr[lane + 64];
    float s = a * a + b * b;
    #pragma unroll
    for (int off = 32; off > 0; off >>= 1) s += __shfl_down(s, off, 64);
    if (lane == 0) x2[row] = s;
}

// ---------------- distance matrix: tiled 128x128 GEMM, batch-per-XCD ----------
__global__ __launch_bounds__(256) void k_dist(const float* __restrict__ X,
                                              const float* __restrict__ x2,
                                              float* __restrict__ D) {
    __shared__ float As[32][132];
    __shared__ float Bs[32][132];
    int b = blockIdx.x & 7;
    int t = blockIdx.x >> 3;
    int ti = t >> 3, tj = t & 7;
    const float* Xb = X + (size_t)b * N_ * C_;
    int tid = threadIdx.x;
    int tx = tid & 15, ty = tid >> 4;
    float acc[8][8];
    #pragma unroll
    for (int i = 0; i < 8; ++i)
        #pragma unroll
        for (int j = 0; j < 8; ++j) acc[i][j] = 0.f;
    for (int kc = 0; kc < 4; ++kc) {
        __syncthreads();
        #pragma unroll
        for (int q = 0; q < 4; ++q) {
            int id = tid + q * 256;
            int r = id >> 3, kk = (id & 7) * 4;
            float4 av = *(const float4*)(Xb + (size_t)(ti * 128 + r) * C_ + kc * 32 + kk);
            As[kk + 0][r] = av.x; As[kk + 1][r] = av.y;
            As[kk + 2][r] = av.z; As[kk + 3][r] = av.w;
            float4 bv = *(const float4*)(Xb + (size_t)(tj * 128 + r) * C_ + kc * 32 + kk);
            Bs[kk + 0][r] = bv.x; Bs[kk + 1][r] = bv.y;
            Bs[kk + 2][r] = bv.z; Bs[kk + 3][r] = bv.w;
        }
        __syncthreads();
        #pragma unroll 8
        for (int k = 0; k < 32; ++k) {
            float a[8], bb[8];
            *(float4*)(a + 0) = *(const float4*)&As[k][ty * 8];
            *(float4*)(a + 4) = *(const float4*)&As[k][ty * 8 + 4];
            *(float4*)(bb + 0) = *(const float4*)&Bs[k][tx * 8];
            *(float4*)(bb + 4) = *(const float4*)&Bs[k][tx * 8 + 4];
            #pragma unroll
            for (int i = 0; i < 8; ++i)
                #pragma unroll
                for (int j = 0; j < 8; ++j) acc[i][j] += a[i] * bb[j];
        }
    }
    float x2r[8], x2c[8];
    #pragma unroll
    for (int i = 0; i < 8; ++i) x2r[i] = x2[b * N_ + ti * 128 + ty * 8 + i];
    #pragma unroll
    for (int j = 0; j < 8; ++j) x2c[j] = x2[b * N_ + tj * 128 + tx * 8 + j];
    #pragma unroll
    for (int i = 0; i < 8; ++i) {
        int m = ti * 128 + ty * 8 + i;
        float* drow = D + ((size_t)(b * N_ + m)) * N_ + tj * 128 + tx * 8;
        float4 o0, o1;
        o0.x = x2r[i] - 2.f * acc[i][0] + x2c[0];
        o0.y = x2r[i] - 2.f * acc[i][1] + x2c[1];
        o0.z = x2r[i] - 2.f * acc[i][2] + x2c[2];
        o0.w = x2r[i] - 2.f * acc[i][3] + x2c[3];
        o1.x = x2r[i] - 2.f * acc[i][4] + x2c[4];
        o1.y = x2r[i] - 2.f * acc[i][5] + x2c[5];
        o1.z = x2r[i] - 2.f * acc[i][6] + x2c[6];
        o1.w = x2r[i] - 2.f * acc[i][7] + x2c[7];
        *(float4*)drow = o0;
        *(float4*)(drow + 4) = o1;
    }
}

// monotone map: float total order -> u32 unsigned order
__device__ __forceinline__ unsigned mapdist(float d) {
    unsigned u = __float_as_uint(d);
    return u ^ (unsigned)(((int)u >> 31) | 0x80000000);
}

// wave-parallel top-m selection thresholds; replicates stable argsort exactly
struct SelThresh { unsigned theta; unsigned psi; };

__device__ __forceinline__ SelThresh wave_topm(const unsigned (&md)[16],
                                               const int (&col)[16], int m) {
    unsigned pfx = 0;
    for (int b = 31; b >= 0; --b) {
        unsigned cand = pfx | (1u << b);
        int c = 0;
        #pragma unroll
        for (int i = 0; i < 16; ++i)
            c += __popcll(__ballot(md[i] < cand));
        if (c < m) pfx = cand;
    }
    unsigned theta = pfx;
    int cLt = 0;
    #pragma unroll
    for (int i = 0; i < 16; ++i)
        cLt += __popcll(__ballot(md[i] < theta));
    int t = m - cLt;  // >= 1
    unsigned ppfx = 0;
    for (int b = 9; b >= 0; --b) {
        unsigned cand = ppfx | (1u << b);
        int c = 0;
        #pragma unroll
        for (int i = 0; i < 16; ++i)
            c += __popcll(__ballot(md[i] == theta && (unsigned)col[i] < cand));
        if (c < t) ppfx = cand;
    }
    return {theta, ppfx};
}

__device__ __forceinline__ void load_row16(const float* __restrict__ Drow, int lane,
                                           unsigned (&md)[16], int (&col)[16]) {
    const float4* row4 = (const float4*)Drow;
    #pragma unroll
    for (int j = 0; j < 4; ++j) {
        float4 v = row4[j * 64 + lane];
        int c0 = (j * 64 + lane) * 4;
        md[j * 4 + 0] = mapdist(v.x); col[j * 4 + 0] = c0 + 0;
        md[j * 4 + 1] = mapdist(v.y); col[j * 4 + 1] = c0 + 1;
        md[j * 4 + 2] = mapdist(v.z); col[j * 4 + 2] = c0 + 2;
        md[j * 4 + 3] = mapdist(v.w); col[j * 4 + 3] = c0 + 3;
    }
}

// ------ top-11 per row -> Dv atomics (wave/row, radix select, batch-XCD) -------
__global__ __launch_bounds__(256) void k_top11dv(const float* __restrict__ D,
                                                 int* __restrict__ Dv) {
    int b = blockIdx.x & 7;
    int n = ((blockIdx.x >> 3) << 2) + (threadIdx.x >> 6);
    int lane = threadIdx.x & 63;
    int w = b * N_ + n;
    unsigned md[16]; int col[16];
    load_row16(D + (size_t)w * N_, lane, md, col);
    SelThresh st = wave_topm(md, col, KNN_);
    #pragma unroll
    for (int i = 0; i < 16; ++i) {
        bool in = (md[i] < st.theta) || (md[i] == st.theta && (unsigned)col[i] <= st.psi);
        if (in) atomicAdd(&Dv[b * N_ + col[i]], 1);
    }
}

// ------- local edge member lists: wave per edge, ordered compaction + pad ------
__global__ void k_locbuild(const float* __restrict__ localH, int* __restrict__ locCnt,
                           unsigned short* __restrict__ locList) {
    int w = (blockIdx.x * blockDim.x + threadIdx.x) >> 6;
    int lane = threadIdx.x & 63;
    if (w >= EL_) return;
    int le = w;
    int base = 0;
    for (int chunk = 0; chunk < N_ / 64; ++chunk) {
        int n = chunk * 64 + lane;
        bool m = localH[(size_t)n * EL_ + le] != 0.0f;
        unsigned long long mask = __ballot(m);
        if (m) {
            int pos = base + __popcll(mask & ((1ull << lane) - 1ull));
            locList[le * 32 + pos] = (unsigned short)n;
        }
        base += __popcll(mask);
    }
    int cp = (base + 7) & ~7;
    for (int t = base + lane; t < cp; t += 64)
        locList[le * 32 + t] = (unsigned short)PADN_;
    if (lane == 0) locCnt[le] = base;
}

// - edge member selection (radix) + ballot-compact + pad + scatter (batch-XCD) --
__global__ __launch_bounds__(256) void k_edgebuild(const float* __restrict__ D,
                                                   const int* __restrict__ Dv,
                                                   const int* __restrict__ locCnt,
                                                   const unsigned short* __restrict__ locList,
                                                   unsigned short* __restrict__ edgeMem,
                                                   int* __restrict__ nodeCnt,
                                                   unsigned short* __restrict__ nodeList,
                                                   float* __restrict__ recipDE) {
    int b = blockIdx.x & 7;
    int e = ((blockIdx.x >> 3) << 2) + (threadIdx.x >> 6);
    int lane = threadIdx.x & 63;
    if (e >= ET_) return;
    int w = b * ET_ + e;
    if (e < N_) {
        int rn = b * N_ + e;
        int full = Dv[rn];
        int m = full < CAP2_ ? full : CAP2_;
        unsigned md[16]; int col[16];
        load_row16(D + (size_t)rn * N_, lane, md, col);
        SelThresh st = wave_topm(md, col, m);
        int base = 0;
        #pragma unroll
        for (int i = 0; i < 16; ++i) {
            bool in = (md[i] < st.theta) || (md[i] == st.theta && (unsigned)col[i] <= st.psi);
            unsigned long long bal = __ballot(in);
            if (in) {
                int pos = base + __popcll(bal & ((1ull << lane) - 1ull));
                edgeMem[(size_t)rn * CAP2_ + pos] = (unsigned short)col[i];
                int p2 = atomicAdd(&nodeCnt[b * N_ + col[i]], 1);
                if (p2 < CAP_) nodeList[((size_t)(b * N_ + col[i])) * CAP_ + p2] = (unsigned short)e;
            }
            base += __popcll(bal);
        }
        int cp = (m + 7) & ~7;
        for (int t = m + lane; t < cp; t += 64)
            edgeMem[(size_t)rn * CAP2_ + t] = (unsigned short)PADN_;
        if (lane == 0) recipDE[w] = 1.0f / (float)full;
    } else {
        int le = e - N_;
        int cnt = locCnt[le];
        for (int t = lane; t < cnt; t += 64) {
            int j = locList[le * 32 + t];
            int pos = atomicAdd(&nodeCnt[b * N_ + j], 1);
            if (pos < CAP_) nodeList[((size_t)(b * N_ + j)) * CAP_ + pos] = (unsigned short)e;
        }
        if (lane == 0) recipDE[w] = 1.0f / (float)cnt;
    }
}

// --- wave-per-node rank sort + pad + recipDV + heavy-row registration ----------
__global__ __launch_bounds__(256) void k_sortlists(int* __restrict__ nodeCnt,
                                                   unsigned short* __restrict__ nodeList,
                                                   float* __restrict__ recipDV,
                                                   const int* __restrict__ Dv,
                                                   int* __restrict__ heavyCnt,
                                                   unsigned* __restrict__ heavyList) {
    __shared__ int sl[4][CAP_];
    int w = threadIdx.x >> 6;
    int lane = threadIdx.x & 63;
    int rn = blockIdx.x * 4 + w;
    int cnt = nodeCnt[rn];
    if (cnt > CAP_) cnt = CAP_;
    unsigned short* g = nodeList + (size_t)rn * CAP_;
    for (int t = lane; t < cnt; t += 64) sl[w][t] = g[t];
    __syncthreads();
    for (int t = lane; t < cnt; t += 64) {
        int v = sl[w][t];
        int rank = 0;
        for (int j = 0; j < cnt; ++j) rank += (sl[w][j] < v) ? 1 : 0;
        g[rank] = (unsigned short)v;
    }
    int cp = (cnt + 7) & ~7;
    for (int t = cnt + lane; t < cp; t += 64)
        g[t] = (unsigned short)PADE_;
    if (lane == 0) {
        recipDV[rn] = 1.0f / (float)cnt;
        nodeCnt[rn] = cnt;
        int b = rn >> 10, n = rn & 1023;
        if (cnt > HT_) {
            int p = atomicAdd(&heavyCnt[b], 1);
            if (p < MAXH_) heavyList[b * MAXH_ + p] = (unsigned)n;           // side 0: node
        }
        int ec = Dv[rn];
        if (ec > CAP2_) ec = CAP2_;
        if (ec > HT_) {
            int p = atomicAdd(&heavyCnt[b], 1);
            if (p < MAXH_) heavyList[b * MAXH_ + p] = 0x10000u | (unsigned)n; // side 1: edge
        }
    }
}

// ---------------- fp32 16-way ILP gather (used by k_einit only; exact cnt) -----
__device__ __forceinline__ float2 gather16(const float* __restrict__ base,
                                           const unsigned short* __restrict__ src,
                                           int cnt, int lane) {
    float2 a0 = {0.f, 0.f}, a1 = {0.f, 0.f}, a2 = {0.f, 0.f}, a3 = {0.f, 0.f};
    const float* bl = base + 2 * lane;
    int t = 0;
    for (; t + 8 <= cnt; t += 8) {
        uint4 u = *(const uint4*)(src + t);
        float2 v0 = *(const float2*)(bl + (size_t)(u.x & 0xFFFFu) * C_);
        float2 v1 = *(const float2*)(bl + (size_t)(u.x >> 16) * C_);
        float2 v2 = *(const float2*)(bl + (size_t)(u.y & 0xFFFFu) * C_);
        float2 v3 = *(const float2*)(bl + (size_t)(u.y >> 16) * C_);
        float2 v4 = *(const float2*)(bl + (size_t)(u.z & 0xFFFFu) * C_);
        float2 v5 = *(const float2*)(bl + (size_t)(u.z >> 16) * C_);
        float2 v6 = *(const float2*)(bl + (size_t)(u.w & 0xFFFFu) * C_);
        float2 v7 = *(const float2*)(bl + (size_t)(u.w >> 16) * C_);
        a0.x += v0.x + v4.x; a0.y += v0.y + v4.y;
        a1.x += v1.x + v5.x; a1.y += v1.y + v5.y;
        a2.x += v2.x + v6.x; a2.y += v2.y + v6.y;
        a3.x += v3.x + v7.x; a3.y += v3.y + v7.y;
    }
    for (; t < cnt; ++t) {
        float2 v = *(const float2*)(bl + (size_t)src[t] * C_);
        a0.x += v.x; a0.y += v.y;
    }
    a0.x += a1.x + a2.x + a3.x;
    a0.y += a1.y + a2.y + a3.y;
    return a0;
}

// ---------------- bf16 mirror helpers ----------------
__device__ __forceinline__ float2 bf2f(unsigned q) {
    return make_float2(__uint_as_float(q << 16), __uint_as_float(q & 0xffff0000u));
}
__device__ __forceinline__ unsigned pack_bf(float x, float y) {
    unsigned ux = __float_as_uint(x), uy = __float_as_uint(y);
    ux += 0x7fffu + ((ux >> 16) & 1u);
    uy += 0x7fffu + ((uy >> 16) & 1u);
    return (ux >> 16) | (uy & 0xffff0000u);
}

// bf16 gather over PADDED list: cntP multiple of 8 (pads hit zero row)
__device__ __forceinline__ float2 gather16h(const unsigned* __restrict__ base,
                                            const unsigned short* __restrict__ src,
                                            int cntP, int lane) {
    float2 a0 = {0.f, 0.f}, a1 = {0.f, 0.f}, a2 = {0.f, 0.f}, a3 = {0.f, 0.f};
    const unsigned* bl = base + lane;
    for (int t = 0; t < cntP; t += 8) {
        uint4 u = *(const uint4*)(src + t);
        unsigned q0 = bl[(size_t)(u.x & 0xFFFFu) * 64];
        unsigned q1 = bl[(size_t)(u.x >> 16) * 64];
        unsigned q2 = bl[(size_t)(u.y & 0xFFFFu) * 64];
        unsigned q3 = bl[(size_t)(u.y >> 16) * 64];
        unsigned q4 = bl[(size_t)(u.z & 0xFFFFu) * 64];
        unsigned q5 = bl[(size_t)(u.z >> 16) * 64];
        unsigned q6 = bl[(size_t)(u.w & 0xFFFFu) * 64];
        unsigned q7 = bl[(size_t)(u.w >> 16) * 64];
        float2 v0 = bf2f(q0), v1 = bf2f(q1), v2 = bf2f(q2), v3 = bf2f(q3);
        float2 v4 = bf2f(q4), v5 = bf2f(q5), v6 = bf2f(q6), v7 = bf2f(q7);
        a0.x += v0.x + v4.x; a0.y += v0.y + v4.y;
        a1.x += v1.x + v5.x; a1.y += v1.y + v5.y;
        a2.x += v2.x + v6.x; a2.y += v2.y + v6.y;
        a3.x += v3.x + v7.x; a3.y += v3.y + v7.y;
    }
    a0.x += a1.x + a2.x + a3.x;
    a0.y += a1.y + a2.y + a3.y;
    return a0;
}

__device__ __forceinline__ void edge_src(const unsigned short* __restrict__ edgeMem,
                                         const int* __restrict__ Dv,
                                         const int* __restrict__ locCnt,
                                         const unsigned short* __restrict__ locList,
                                         int b, int e,
                                         const unsigned short*& src, int& cnt) {
    if (e < N_) {
        int rn = b * N_ + e;
        cnt = Dv[rn];
        if (cnt > CAP2_) cnt = CAP2_;
        src = edgeMem + (size_t)rn * CAP2_;
    } else {
        cnt = locCnt[e - N_];
        src = locList + (e - N_) * 32;
    }
}

// ---------------- E init: E0 = W_ev @ X (fp32 gather; one-shot) ----------------
__global__ void k_einit(const float* __restrict__ Xsrc, float* __restrict__ Edst,
                        const unsigned short* __restrict__ edgeMem, const int* __restrict__ Dv,
                        const int* __restrict__ locCnt, const unsigned short* __restrict__ locList,
                        const float* __restrict__ recipDE) {
    int b = blockIdx.x & 7;
    int e = (blockIdx.x >> 3) * 2 + (threadIdx.x >> 6);
    int lane = threadIdx.x & 63;
    if (e >= ET_) return;
    int w = b * ET_ + e;
    const unsigned short* src; int cnt;
    edge_src(edgeMem, Dv, locCnt, locList, b, e, src, cnt);
    float2 acc = gather16(Xsrc + (size_t)b * N_ * C_, src, cnt, lane);
    float r = recipDE[w];
    *(float2*)(Edst + (size_t)w * C_ + 2 * lane) = make_float2(r * acc.x, r * acc.y);
}

// -- fused diffusion step: in-place fp32 state, padded-list bf16 mirror gathers -
constexpr int LIGHTB_ = B_ * ((RT_ + 7) / 8);  // 8 * 281 = 2248
__global__ __launch_bounds__(512) void k_step(float* __restrict__ X,
                                              float* __restrict__ E,
                                              const unsigned* __restrict__ XhSrc,
                                              const unsigned* __restrict__ EhSrc,
                                              unsigned* __restrict__ XhDst,
                                              unsigned* __restrict__ EhDst,
                                              const unsigned short* __restrict__ edgeMem,
                                              const int* __restrict__ Dv,
                                              const int* __restrict__ locCnt,
                                              const unsigned short* __restrict__ locList,
                                              const int* __restrict__ nodeCnt,
                                              const unsigned short* __restrict__ nodeList,
                                              const float* __restrict__ recipDV,
                                              const float* __restrict__ recipDE,
                                              const int* __restrict__ heavyCnt,
                                              const unsigned* __restrict__ heavyList) {
    __shared__ float2 ps[8][64];
    int lane = threadIdx.x & 63;
    int wid = threadIdx.x >> 6;
    if (blockIdx.x < (unsigned)LIGHTB_) {
        int b = blockIdx.x & 7;
        int local = ((blockIdx.x >> 3) << 3) + wid;  // 0..RT_-1 (+pad)
        if (local >= RT_) return;
        if (local < N_) {
            int rn = b * N_ + local;
            int cnt = nodeCnt[rn];
            if (cnt > HT_) return;  // heavy block handles
            float2 acc = gather16h(EhSrc + (size_t)b * EMS_ * 64, nodeList + (size_t)rn * CAP_,
                                   (cnt + 7) & ~7, lane);
            size_t o = (size_t)rn * C_ + 2 * lane;
            float2 xv = *(const float2*)(X + o);
            float s = 0.05f * recipDV[rn];
            float rx = 0.95f * xv.x + s * acc.x, ry = 0.95f * xv.y + s * acc.y;
            *(float2*)(X + o) = make_float2(rx, ry);
            XhDst[((size_t)b * XMS_ + local) * 64 + lane] = pack_bf(rx, ry);
        } else {
            int e = local - N_;
            int be = b * ET_ + e;
            const unsigned short* src; int cnt;
            edge_src(edgeMem, Dv, locCnt, locList, b, e, src, cnt);
            if (cnt > HT_) return;  // heavy block handles
            float2 acc = gather16h(XhSrc + (size_t)b * XMS_ * 64, src, (cnt + 7) & ~7, lane);
            size_t o = (size_t)be * C_ + 2 * lane;
            float2 ev = *(const float2*)(E + o);
            float s = 0.9f * recipDE[be];
            float rx = 0.1f * ev.x + s * acc.x, ry = 0.1f * ev.y + s * acc.y;
            *(float2*)(E + o) = make_float2(rx, ry);
            EhDst[((size_t)b * EMS_ + e) * 64 + lane] = pack_bf(rx, ry);
        }
    } else {
        int hb = blockIdx.x - LIGHTB_;
        int b = hb & 7;
        int idx = hb >> 3;
        if (idx >= heavyCnt[b]) return;        // whole-block uniform return
        unsigned enc = heavyList[b * MAXH_ + idx];
        int side = (int)(enc >> 16), n = (int)(enc & 0xFFFFu);
        const unsigned short* src;
        const unsigned* gbase;
        const float* fsrc;
        float scale, selfw;
        size_t orow, mrow;
        int cnt;
        if (side == 0) {  // node n
            int rn = b * N_ + n;
            cnt = nodeCnt[rn];
            src = nodeList + (size_t)rn * CAP_;
            gbase = EhSrc + (size_t)b * EMS_ * 64;
            scale = 0.05f * recipDV[rn]; selfw = 0.95f;
            orow = (size_t)rn * C_; fsrc = X;
            mrow = ((size_t)b * XMS_ + n) * 64;
        } else {          // kNN edge e = n
            int rn = b * N_ + n;
            int be = b * ET_ + n;
            cnt = Dv[rn]; if (cnt > CAP2_) cnt = CAP2_;
            src = edgeMem + (size_t)rn * CAP2_;
            gbase = XhSrc + (size_t)b * XMS_ * 64;
            scale = 0.9f * recipDE[be]; selfw = 0.1f;
            orow = (size_t)be * C_; fsrc = E;
            mrow = ((size_t)b * EMS_ + n) * 64;
        }
        int cntP = (cnt + 7) & ~7;
        int per = (((cntP >> 3) + 7) >> 3) << 3;  // 8-aligned per-wave slice
        int st = wid * per;
        int ln = cntP - st;
        if (ln < 0) ln = 0;
        if (ln > per) ln = per;
        ps[wid][lane] = gather16h(gbase, src + st, ln, lane);
        __syncthreads();
        if (wid == 0) {
            float ax = 0.f, ay = 0.f;
            #pragma unroll
            for (int q = 0; q < 8; ++q) { ax += ps[q][lane].x; ay += ps[q][lane].y; }
            float2 sv = *(const float2*)(fsrc + orow + 2 * lane);
            float rx = selfw * sv.x + scale * ax, ry = selfw * sv.y + scale * ay;
            float* fdst = (side == 0) ? (float*)X : (float*)E;
            unsigned* hdst = (side == 0) ? XhDst : EhDst;
            *(float2*)(fdst + orow + 2 * lane) = make_float2(rx, ry);
            hdst[mrow + lane] = pack_bf(rx, ry);
        }
    }
}

// ------- Z = Z + relu(Z @ W^T + bias): 16 rows/block, W amortized 16x ---------
constexpr int XB_ = B_ * N_ / 16;   // 512
constexpr int EB_ = B_ * ET_ / 16;  // 610
__global__ __launch_bounds__(128) void k_transform(float* __restrict__ Xz,
                                                   float* __restrict__ Ez,
                                                   const float* __restrict__ tvw,
                                                   const float* __restrict__ tvb,
                                                   const float* __restrict__ tew,
                                                   const float* __restrict__ teb) {
    __shared__ __align__(16) float zs[16][C_];
    int blk = blockIdx.x;
    float* Z;
    const float *W, *bias;
    if (blk < XB_) { Z = Xz + (size_t)blk * 16 * C_; W = tvw; bias = tvb; }
    else { Z = Ez + (size_t)(blk - XB_) * 16 * C_; W = tew; bias = teb; }
    int c = threadIdx.x;
    const float4* Zg4 = (const float4*)Z;
    float4* zs4 = (float4*)zs;
    #pragma unroll
    for (int q = 0; q < 4; ++q) zs4[c + q * 128] = Zg4[c + q * 128];
    __syncthreads();
    float acc[16];
    float bc = bias[c];
    #pragma unroll
    for (int r = 0; r < 16; ++r) acc[r] = bc;
    const float4* w4 = (const float4*)(W + (size_t)c * C_);
    #pragma unroll 4
    for (int k = 0; k < 32; ++k) {
        float4 w = w4[k];
        #pragma unroll
        for (int r = 0; r < 16; ++r) {
            float4 z = ((const float4*)zs[r])[k];
            acc[r] += w.x * z.x + w.y * z.y + w.z * z.z + w.w * z.w;
        }
    }
    #pragma unroll
    for (int r = 0; r < 16; ++r)
        Z[(size_t)r * C_ + c] = zs[r][c] + fmaxf(acc[r], 0.f);
}

// ---- bn_nodes: per-position norm over (B, C); also refreshes bf16 mirrors -----
__global__ void k_bn(float* __restrict__ Xz, float* __restrict__ Ez,
                     unsigned* __restrict__ Xh, unsigned* __restrict__ Eh) {
    int pos = blockIdx.x;
    float* Z;
    unsigned* Zh;
    int P, MS;
    if (pos < N_) { Z = Xz; Zh = Xh; P = N_; MS = XMS_; }
    else { Z = Ez; Zh = Eh; P = ET_; MS = EMS_; pos -= N_; }
    int t = threadIdx.x;
    __shared__ float red[256];
    float2 v[2];
    #pragma unroll
    for (int q = 0; q < 2; ++q) {
        int f = t + q * 256;
        int b = f >> 6, cp = f & 63;
        v[q] = *(const float2*)(Z + ((size_t)(b * P + pos)) * C_ + 2 * cp);
    }
    red[t] = v[0].x + v[0].y + v[1].x + v[1].y;
    __syncthreads();
    for (int off = 128; off > 0; off >>= 1) {
        if (t < off) red[t] += red[t + off];
        __syncthreads();
    }
    float m = red[0] * (1.0f / 1024.0f);
    __syncthreads();
    float s2 = 0.f;
    #pragma unroll
    for (int q = 0; q < 2; ++q) {
        float dx = v[q].x - m, dy = v[q].y - m;
        s2 += dx * dx + dy * dy;
    }
    red[t] = s2;
    __syncthreads();
    for (int off = 128; off > 0; off >>= 1) {
        if (t < off) red[t] += red[t + off];
        __syncthreads();
    }
    float rstd = rsqrtf(red[0] * (1.0f / 1024.0f) + 1e-5f);
    #pragma unroll
    for (int q = 0; q < 2; ++q) {
        int f = t + q * 256;
        int b = f >> 6, cp = f & 63;
        float rx = (v[q].x - m) * rstd, ry = (v[q].y - m) * rstd;
        *(float2*)(Z + ((size_t)(b * P + pos)) * C_ + 2 * cp) = make_float2(rx, ry);
        Zh[((size_t)b * MS + pos) * 64 + cp] = pack_bf(rx, ry);
    }
}

// ---------------- final per-channel stats over (B,N) ----------------
__global__ void k_finstats(const float* __restrict__ Xf, float* __restrict__ stats) {
    int c = blockIdx.x;
    int t = threadIdx.x;
    __shared__ float rs[256], rs2[256];
    float s = 0.f, s2 = 0.f;
    for (int r = t; r < B_ * N_; r += 256) {
        float x = Xf[(size_t)r * C_ + c];
        s += x;
        s2 += x * x;
    }
    rs[t] = s; rs2[t] = s2;
    __syncthreads();
    for (int off = 128; off > 0; off >>= 1) {
        if (t < off) { rs[t] += rs[t + off]; rs2[t] += rs2[t + off]; }
        __syncthreads();
    }
    if (t == 0) {
        float m = rs[0] / (float)(B_ * N_);
        float var = rs2[0] / (float)(B_ * N_) - m * m;
        stats[c] = m;
        stats[C_ + c] = rsqrtf(var + 1e-5f);
    }
}

__global__ void k_finapply(const float* __restrict__ Xf, const float* __restrict__ Xin,
                           const float* __restrict__ stats, const float* __restrict__ bnw,
                           const float* __restrict__ bnb, float* __restrict__ out) {
    size_t i = (size_t)blockIdx.x * blockDim.x + threadIdx.x;
    if (i >= (size_t)B_ * N_ * C_) return;
    int c = (int)(i & (C_ - 1));
    float x = Xf[i];
    float xn = (x - stats[c]) * stats[C_ + c] * bnw[c] + bnb[c];
    out[i] = fmaxf(xn, 0.f) + Xin[i];
}

extern "C" void kernel_launch(void* const* d_in, const int* in_sizes, int n_in,
                              void* d_out, int out_size, void* d_ws, size_t ws_size,
                              hipStream_t stream) {
    const float* Xin = (const float*)d_in[0];
    const float* localH = (const float*)d_in[1];
    const float* tv_w = (const float*)d_in[2];
    const float* tv_b = (const float*)d_in[3];
    const float* te_w = (const float*)d_in[4];
    const float* te_b = (const float*)d_in[5];
    const float* bn_w = (const float*)d_in[6];
    const float* bn_b = (const float*)d_in[7];
    float* out = (float*)d_out;

    char* base = (char*)d_ws;
    size_t off = 0;
    auto alloc = [&](size_t bytes) -> void* {
        void* p = base + off;
        off = (off + bytes + 255) & ~(size_t)255;
        return p;
    };
    float* D = (float*)alloc((size_t)B_ * N_ * N_ * 4);
    float* x2 = (float*)alloc((size_t)B_ * N_ * 4);
    int* Dv = (int*)alloc((size_t)B_ * N_ * 4);
    int* nodeCnt = (int*)alloc((size_t)B_ * N_ * 4);
    unsigned short* nodeList = (unsigned short*)alloc((size_t)B_ * N_ * CAP_ * 2);
    float* recipDV = (float*)alloc((size_t)B_ * N_ * 4);
    float* recipDE = (float*)alloc((size_t)B_ * ET_ * 4);
    int* locCnt = (int*)alloc(256 * 4);
    unsigned short* locList = (unsigned short*)alloc((size_t)EL_ * 32 * 2);
    unsigned short* edgeMem = (unsigned short*)alloc((size_t)B_ * N_ * CAP2_ * 2);
    int* heavyCnt = (int*)alloc(B_ * 4);
    unsigned* heavyList = (unsigned*)alloc((size_t)B_ * MAXH_ * 4);
    float* X0 = (float*)alloc((size_t)B_ * N_ * C_ * 4);
    float* E0 = (float*)alloc((size_t)B_ * ET_ * C_ * 4);
    unsigned* Xh0 = (unsigned*)alloc((size_t)B_ * XMS_ * 64 * 4);
    unsigned* Xh1 = (unsigned*)alloc((size_t)B_ * XMS_ * 64 * 4);
    unsigned* Eh0 = (unsigned*)alloc((size_t)B_ * EMS_ * 64 * 4);
    unsigned* Eh1 = (unsigned*)alloc((size_t)B_ * EMS_ * 64 * 4);
    float* stats = (float*)alloc(2 * C_ * 4);
    if (off > ws_size) return;

    hipMemsetAsync(Dv, 0, (size_t)B_ * N_ * 4, stream);
    hipMemsetAsync(nodeCnt, 0, (size_t)B_ * N_ * 4, stream);
    hipMemsetAsync(heavyCnt, 0, B_ * 4, stream);
    // zero mirror buffers once: pad rows must stay zero across all steps
    hipMemsetAsync(Xh0, 0, (size_t)B_ * XMS_ * 64 * 4, stream);
    hipMemsetAsync(Xh1, 0, (size_t)B_ * XMS_ * 64 * 4, stream);
    hipMemsetAsync(Eh0, 0, (size_t)B_ * EMS_ * 64 * 4, stream);
    hipMemsetAsync(Eh1, 0, (size_t)B_ * EMS_ * 64 * 4, stream);
    hipMemcpyAsync(X0, Xin, (size_t)B_ * N_ * C_ * 4, hipMemcpyDeviceToDevice, stream);

    k_x2<<<B_ * N_ / 4, 256, 0, stream>>>(Xin, x2);
    k_dist<<<B_ * 64, 256, 0, stream>>>(Xin, x2, D);
    k_top11dv<<<B_ * (N_ / 4), 256, 0, stream>>>(D, Dv);
    k_locbuild<<<(EL_ * 64 + 255) / 256, 256, 0, stream>>>(localH, locCnt, locList);
    k_edgebuild<<<B_ * ((ET_ + 3) / 4), 256, 0, stream>>>(D, Dv, locCnt, locList, edgeMem,
                                                          nodeCnt, nodeList, recipDE);
    k_sortlists<<<B_ * N_ / 4, 256, 0, stream>>>(nodeCnt, nodeList, recipDV, Dv,
                                                 heavyCnt, heavyList);
    k_einit<<<B_ * (ET_ / 2 + 1), 128, 0, stream>>>(X0, E0, edgeMem, Dv, locCnt, locList,
                                                    recipDE);

    unsigned* Xhc = Xh0; unsigned* Xhn = Xh1; unsigned* Ehc = Eh0; unsigned* Ehn = Eh1;
    const int STEPG = LIGHTB_ + 8 * MAXH_;
    for (int i = 0; i < 40; ++i) {
        if (i % 20 == 0) {
            k_transform<<<XB_ + EB_, 128, 0, stream>>>(X0, E0, tv_w, tv_b, te_w, te_b);
            k_bn<<<N_ + ET_, 256, 0, stream>>>(X0, E0, Xhc, Ehc);
        }
        k_step<<<STEPG, 512, 0, stream>>>(X0, E0, Xhc, Ehc, Xhn, Ehn,
                                          edgeMem, Dv, locCnt, locList, nodeCnt,
                                          nodeList, recipDV, recipDE, heavyCnt, heavyList);
        unsigned* th;
        th = Xhc; Xhc = Xhn; Xhn = th;
        th = Ehc; Ehc = Ehn; Ehn = th;
    }

    k_finstats<<<C_, 256, 0, stream>>>(X0, stats);
    k_finapply<<<(B_ * N_ * C_ + 255) / 256, 256, 0, stream>>>(X0, Xin, stats, bn_w, bn_b, out);
}